// Round 2
// baseline (1448.984 us; speedup 1.0000x reference)
//
#include <hip/hip_runtime.h>
#include <hip/hip_bf16.h>

#define IN_F 4096
#define OUT_F 11008
#define M_TOT 8192            // 4 * 2048
#define NGROUPS 2818048       // OUT_F * IN_F / 16

#define AS1 __attribute__((address_space(1)))
#define AS3 __attribute__((address_space(3)))

typedef __attribute__((ext_vector_type(4))) float f32x4;
typedef __attribute__((ext_vector_type(8))) __bf16 bf16x8;
typedef __attribute__((ext_vector_type(4))) int i32x4;
typedef __attribute__((ext_vector_type(8))) unsigned short u16x8;

__device__ __forceinline__ unsigned short f2bf(float f) {
  union { float f; unsigned u; } v;
  v.f = f;
  unsigned u = v.u;
  return (unsigned short)((u + 0x7FFFu + ((u >> 16) & 1u)) >> 16);  // RNE
}

// ---------------------------------------------------------------- x: f32 -> bf16
__global__ void k_cvt_x(const float* __restrict__ x, unsigned short* __restrict__ xb) {
  const int t = blockIdx.x * 256 + threadIdx.x;   // exactly M_TOT*IN_F/8 threads
  const f32x4* p = (const f32x4*)(x + (size_t)t * 8);
  f32x4 a = p[0], b = p[1];
  u16x8 o;
  o[0] = f2bf(a[0]); o[1] = f2bf(a[1]); o[2] = f2bf(a[2]); o[3] = f2bf(a[3]);
  o[4] = f2bf(b[0]); o[5] = f2bf(b[1]); o[6] = f2bf(b[2]); o[7] = f2bf(b[3]);
  *(u16x8*)(xb + (size_t)t * 8) = o;
}

// ------------------------------------------------- dequant 3-bit -> bf16 [OUT_F][IN_F]
__global__ void k_deq(const int* __restrict__ q3, const float* __restrict__ nrm,
                      unsigned short* __restrict__ wb) {
  const int g = blockIdx.x * 256 + threadIdx.x;   // exactly NGROUPS threads
  const i32x4* qp = (const i32x4*)(q3 + (size_t)g * 8);
  i32x4 qa = qp[0], qb = qp[1];
  const float nm = nrm[g];
  const float s = nm * (2.0f / 7.0f);             // w = q*s - nm
  u16x8 o0, o1;
#define DQ2(v, oo, idx)                                              \
  {                                                                  \
    int _v = (v);                                                    \
    oo[idx]     = f2bf((float)(_v & 7) * s - nm);                    \
    oo[idx + 1] = f2bf((float)((_v >> 3) & 7) * s - nm);             \
  }
  DQ2(qa[0], o0, 0) DQ2(qa[1], o0, 2) DQ2(qa[2], o0, 4) DQ2(qa[3], o0, 6)
  DQ2(qb[0], o1, 0) DQ2(qb[1], o1, 2) DQ2(qb[2], o1, 4) DQ2(qb[3], o1, 6)
#undef DQ2
  u16x8* w8 = (u16x8*)(wb + (size_t)g * 16);
  w8[0] = o0;
  w8[1] = o1;
}

// ---------------------------------------------------------------- bf16 GEMM (m97 structure)
// C[M][N] = A[M][K] * B[N][K]^T + bias;  BM=BN=128, BK=32, 4 waves, 16x16x32 MFMA
#define BM 128
#define BN 128
#define BK 32

__global__ __launch_bounds__(256) void k_gemm(const unsigned short* __restrict__ A,
                                              const unsigned short* __restrict__ B,
                                              const float* __restrict__ bias,
                                              float* __restrict__ C) {
  __shared__ unsigned short As[BM * BK];  // [128][32] bf16, 8 KB
  __shared__ unsigned short Bs[BN * BK];  // [128][32] bf16, 8 KB

  const int tid  = threadIdx.x;
  const int lane = tid & 63;
  const int wid  = tid >> 6;
  const int wr   = wid >> 1;       // wave row in 2x2
  const int wc   = wid & 1;        // wave col
  const int tile_m = blockIdx.y * BM;
  const int tile_n = blockIdx.x * BN;

  f32x4 acc[4][4];
#pragma unroll
  for (int m = 0; m < 4; ++m)
#pragma unroll
    for (int n = 0; n < 4; ++n) acc[m][n] = {0.0f, 0.0f, 0.0f, 0.0f};

  // Staging: tile is 512 granules of 16B; thread t covers granule t and 256+t.
  // granule idx -> row = idx>>2, k-offset = (idx&3)*8. LDS dest = linear idx*16B
  // = wave-uniform base + lane*16 (required by global_load_lds).
  const int r0 = tid >> 2;              // 0..63
  const int gc = (tid & 3) * 8;         // k element offset
  const unsigned short* a0 = A + (size_t)(tile_m + r0) * IN_F + gc;
  const unsigned short* a1 = A + (size_t)(tile_m + 64 + r0) * IN_F + gc;
  const unsigned short* b0 = B + (size_t)(tile_n + r0) * IN_F + gc;
  const unsigned short* b1 = B + (size_t)(tile_n + 64 + r0) * IN_F + gc;

  AS3 unsigned short* As3 = (AS3 unsigned short*)As;
  AS3 unsigned short* Bs3 = (AS3 unsigned short*)Bs;
  AS3 unsigned short* dA0 = As3 + (size_t)tid * 8;
  AS3 unsigned short* dA1 = As3 + (size_t)(256 + tid) * 8;
  AS3 unsigned short* dB0 = Bs3 + (size_t)tid * 8;
  AS3 unsigned short* dB1 = Bs3 + (size_t)(256 + tid) * 8;

  // Fragment read bases: lane l&15 = row-in-fragment, (l>>4)*8 = k offset
  const int lr = lane & 15;
  const int lk = (lane >> 4) * 8;
  const unsigned short* Ars = As + (wr * 64 + lr) * BK + lk;
  const unsigned short* Brs = Bs + (wc * 64 + lr) * BK + lk;

  for (int kt = 0; kt < IN_F / BK; ++kt) {
    const int ko = kt * BK;
    __builtin_amdgcn_global_load_lds((const AS1 void*)(a0 + ko), (AS3 void*)dA0, 16, 0, 0);
    __builtin_amdgcn_global_load_lds((const AS1 void*)(a1 + ko), (AS3 void*)dA1, 16, 0, 0);
    __builtin_amdgcn_global_load_lds((const AS1 void*)(b0 + ko), (AS3 void*)dB0, 16, 0, 0);
    __builtin_amdgcn_global_load_lds((const AS1 void*)(b1 + ko), (AS3 void*)dB1, 16, 0, 0);
    __syncthreads();  // drains vmcnt(0) -> staged data visible

    bf16x8 af[4], bfr[4];
#pragma unroll
    for (int m = 0; m < 4; ++m) af[m] = *(const bf16x8*)(Ars + m * 16 * BK);
#pragma unroll
    for (int n = 0; n < 4; ++n) bfr[n] = *(const bf16x8*)(Brs + n * 16 * BK);

#pragma unroll
    for (int m = 0; m < 4; ++m)
#pragma unroll
      for (int n = 0; n < 4; ++n)
        acc[m][n] = __builtin_amdgcn_mfma_f32_16x16x32_bf16(af[m], bfr[n], acc[m][n], 0, 0, 0);

    __syncthreads();  // all waves done reading before next-stage overwrite
  }

  // Epilogue: C/D layout (m89/m91): col = lane&15, row = (lane>>4)*4 + reg
  const int orow0 = tile_m + wr * 64 + ((lane >> 4) << 2);
  const int ocol0 = tile_n + wc * 64 + (lane & 15);
#pragma unroll
  for (int n = 0; n < 4; ++n) {
    const int oc = ocol0 + n * 16;
    const float bv = bias[oc];
#pragma unroll
    for (int m = 0; m < 4; ++m) {
      const int orb = orow0 + m * 16;
      f32x4 v = acc[m][n];
#pragma unroll
      for (int i = 0; i < 4; ++i) C[(size_t)(orb + i) * OUT_F + oc] = v[i] + bv;
    }
  }
}

// ---------------------------------------------------------------- slow correct fallback
__global__ void k_fallback(const float* __restrict__ x, const int* __restrict__ q3,
                           const float* __restrict__ nrm, const float* __restrict__ bias,
                           float* __restrict__ C) {
  const long long t = (long long)blockIdx.x * 256 + threadIdx.x;
  if (t >= (long long)M_TOT * OUT_F) return;
  const int m = (int)(t / OUT_F);
  const int o = (int)(t % OUT_F);
  const float* xr = x + (size_t)m * IN_F;
  const int gbase = o * (IN_F / 16);
  float accv = 0.0f;
  for (int g = 0; g < IN_F / 16; ++g) {
    const float nm = nrm[gbase + g];
    const float s = nm * (2.0f / 7.0f);
    const int* q = q3 + (size_t)(gbase + g) * 8;
#pragma unroll
    for (int j = 0; j < 8; ++j) {
      const int v = q[j];
      accv += xr[g * 16 + 2 * j] * ((float)(v & 7) * s - nm);
      accv += xr[g * 16 + 2 * j + 1] * ((float)((v >> 3) & 7) * s - nm);
    }
  }
  C[t] = accv + bias[o];
}

// ----------------------------------------------------------------------------
extern "C" void kernel_launch(void* const* d_in, const int* in_sizes, int n_in,
                              void* d_out, int out_size, void* d_ws, size_t ws_size,
                              hipStream_t stream) {
  const float* x    = (const float*)d_in[0];
  const int* q3     = (const int*)d_in[1];
  const float* nrm  = (const float*)d_in[2];
  const float* bias = (const float*)d_in[3];
  float* C = (float*)d_out;

  const size_t xb_elems = (size_t)M_TOT * IN_F;       // 33,554,432
  const size_t wb_elems = (size_t)OUT_F * IN_F;       // 45,088,768
  const size_t need = (xb_elems + wb_elems) * sizeof(unsigned short);  // 150 MiB

  if (ws_size >= need) {
    unsigned short* xb = (unsigned short*)d_ws;
    unsigned short* wb = xb + xb_elems;
    k_cvt_x<<<(unsigned)(xb_elems / 8 / 256), 256, 0, stream>>>(x, xb);
    k_deq<<<NGROUPS / 256, 256, 0, stream>>>(q3, nrm, wb);
    dim3 grid(OUT_F / BN, M_TOT / BM);  // 86 x 64
    k_gemm<<<grid, 256, 0, stream>>>(xb, wb, bias, C);
  } else {
    const long long total = (long long)M_TOT * OUT_F;  // 90,177,536 (multiple of 256)
    k_fallback<<<(unsigned)(total / 256), 256, 0, stream>>>(x, q3, nrm, bias, C);
  }
}